// Round 16
// baseline (272.556 us; speedup 1.0000x reference)
//
#include <hip/hip_runtime.h>

// GAN hinge loss reduction, two-stage (no global atomics):
//   contrib = (t==+1) ? min(0, D-1) : (t==-1) ? min(0, -1-D) : 0
//   out[0]  = sum(contrib) / N
// N = 2^25, fp32 + int32 -> fp32 scalar. 268 MB read, memory-bound.
//
// History: R4 110us (atomic tail) -> R7 96us (partials) -> R9 ~70us
// (contiguous 2KB/wave bursts + NT, CONFOUNDED A/B) -> R13 8-load burst
// null (ILP not the limiter; serving-rate limited).
// This round: NT-ablation. Harness restore leaves HALF the input L3-resident
// (FETCH_SIZE 131MB vs 268MB); if the nt flag bypasses cache lookup, that
// half is demoted to HBM. Same layout as R13, plain temporal loads.
//
// Math: for t in {-1,+1}, t*(D-t) = t*D - 1 => contrib = min(0, t*D - 1),
// masked by (t*t==1) to preserve exact reference semantics for other t.

typedef float  vfloat4 __attribute__((ext_vector_type(4)));
typedef int    vint4   __attribute__((ext_vector_type(4)));

__device__ __forceinline__ float chunk_contrib(vfloat4 d, vint4 t) {
  float c0 = (t.x * t.x == 1) ? fminf(0.0f, __fmaf_rn((float)t.x, d.x, -1.0f)) : 0.0f;
  float c1 = (t.y * t.y == 1) ? fminf(0.0f, __fmaf_rn((float)t.y, d.y, -1.0f)) : 0.0f;
  float c2 = (t.z * t.z == 1) ? fminf(0.0f, __fmaf_rn((float)t.z, d.z, -1.0f)) : 0.0f;
  float c3 = (t.w * t.w == 1) ? fminf(0.0f, __fmaf_rn((float)t.w, d.w, -1.0f)) : 0.0f;
  return (c0 + c1) + (c2 + c3);
}

__global__ __launch_bounds__(256) void ganloss_partial(
    const float* __restrict__ D, const int* __restrict__ T,
    float* __restrict__ partials, int n4) {
  const vfloat4* __restrict__ D4 = reinterpret_cast<const vfloat4*>(D);
  const vint4* __restrict__ T4 = reinterpret_cast<const vint4*>(T);

  int lane = threadIdx.x & 63;
  int wid = threadIdx.x >> 6;
  int gwave = blockIdx.x * 4 + wid;          // global wave id
  int nwaves = gridDim.x * 4;                 // 8192 waves
  // each wave owns 256 consecutive chunks per iteration:
  // 4KB contiguous per stream, 8 TEMPORAL loads issued before any consume.

  float acc = 0.0f;
  for (int k = gwave; k * 256 < n4; k += nwaves) {
    int base = k * 256;
    vfloat4 d0 = D4[base + lane];
    vfloat4 d1 = D4[base + 64 + lane];
    vfloat4 d2 = D4[base + 128 + lane];
    vfloat4 d3 = D4[base + 192 + lane];
    vint4 t0 = T4[base + lane];
    vint4 t1 = T4[base + 64 + lane];
    vint4 t2 = T4[base + 128 + lane];
    vint4 t3 = T4[base + 192 + lane];
    acc += chunk_contrib(d0, t0);
    acc += chunk_contrib(d1, t1);
    acc += chunk_contrib(d2, t2);
    acc += chunk_contrib(d3, t3);
  }

  // wave-64 butterfly reduce
  #pragma unroll
  for (int off = 32; off > 0; off >>= 1)
    acc += __shfl_down(acc, off, 64);

  __shared__ float wsum[4];  // 256 threads = 4 waves
  if (lane == 0) wsum[wid] = acc;
  __syncthreads();

  if (threadIdx.x == 0)
    partials[blockIdx.x] = (wsum[0] + wsum[1]) + (wsum[2] + wsum[3]);
}

__global__ __launch_bounds__(256) void ganloss_final(
    const float* __restrict__ partials, float* __restrict__ out,
    int nparts, float inv_n) {
  float acc = 0.0f;
  for (int i = threadIdx.x; i < nparts; i += 256)
    acc += partials[i];

  #pragma unroll
  for (int off = 32; off > 0; off >>= 1)
    acc += __shfl_down(acc, off, 64);

  __shared__ float wsum[4];
  int lane = threadIdx.x & 63;
  int wid = threadIdx.x >> 6;
  if (lane == 0) wsum[wid] = acc;
  __syncthreads();

  if (threadIdx.x == 0)
    out[0] = ((wsum[0] + wsum[1]) + (wsum[2] + wsum[3])) * inv_n;
}

extern "C" void kernel_launch(void* const* d_in, const int* in_sizes, int n_in,
                              void* d_out, int out_size, void* d_ws, size_t ws_size,
                              hipStream_t stream) {
  const float* D = (const float*)d_in[0];
  const int* T = (const int*)d_in[1];
  float* out = (float*)d_out;
  float* partials = (float*)d_ws;  // 2048 * 4 B = 8 KB scratch
  int n = in_sizes[0];             // 33554432
  int n4 = n >> 2;                 // 8388608 chunks
  float inv_n = 1.0f / (float)n;

  const int block = 256;
  const int grid = 2048;  // 8192 waves; 4 iterations of 256 chunks each

  ganloss_partial<<<grid, block, 0, stream>>>(D, T, partials, n4);
  // same-stream ordering makes partials visible; out[0] written
  // unconditionally (no memset of the poisoned d_out needed).
  ganloss_final<<<1, block, 0, stream>>>(partials, out, grid, inv_n);
}